// Round 1
// baseline (967.693 us; speedup 1.0000x reference)
//
#include <hip/hip_runtime.h>
#include <hip/hip_bf16.h>
#include <stdint.h>

// ---------------------------------------------------------------------------
// AttendedSeqEmbedding: ragged bidirectional GRU + MLP + attention pooling
// I=128, H=64, O=128, B=512, T<=512
// Phases:
//   K0 offsets   : prefix-sum of seqlens
//   K1 prep      : f32 -> bf16 hi/lo weight splits, fused gate biases
//   K2 gemm_gx   : gx[tok][384] = x @ [Wih_f;Wih_b]^T + biases (MFMA hi/lo)
//   K3 scan      : 1024 scans batched 16-wide as MFMA N-dim, h in LDS dbuf
//   K4 gemm_mlp  : mlp[tok][128] = tanh(hs @ Wm^T + bm), scores = mlp . ctx
//   K5 pool      : per-seq softmax(scores) weighted sum of mlp rows
// ---------------------------------------------------------------------------

typedef __attribute__((ext_vector_type(8))) short short8;
typedef __attribute__((ext_vector_type(4))) float f32x4;

__device__ __forceinline__ unsigned short f2bf(float f) {
  unsigned int u = __float_as_uint(f);
  u = (u + 0x7FFFu + ((u >> 16) & 1u)) >> 16;
  return (unsigned short)u;
}
__device__ __forceinline__ float bf2f(unsigned short h) {
  return __uint_as_float(((unsigned int)h) << 16);
}
__device__ __forceinline__ void f2bf2(float f, unsigned short& hi, unsigned short& lo) {
  hi = f2bf(f);
  lo = f2bf(f - bf2f(hi));
}
__device__ __forceinline__ f32x4 mfma16(short8 a, short8 b, f32x4 c) {
  return __builtin_amdgcn_mfma_f32_16x16x32_bf16(a, b, c, 0, 0, 0);
}
__device__ __forceinline__ float sigm(float x) { return 1.f / (1.f + __expf(-x)); }
__device__ __forceinline__ float tanhft(float x) {
  float e = __expf(2.f * x);
  return 1.f - 2.f / (e + 1.f);
}
__device__ __forceinline__ unsigned int pack2(unsigned short a, unsigned short b) {
  return (unsigned int)a | ((unsigned int)b << 16);
}

// ---------------------------------------------------------------- K0: offsets
__global__ void k_offsets(const int* __restrict__ seqlens, int* __restrict__ off) {
  __shared__ int s[512];
  int t = threadIdx.x;
  s[t] = seqlens[t];
  __syncthreads();
  for (int d = 1; d < 512; d <<= 1) {
    int v = (t >= d) ? s[t - d] : 0;
    __syncthreads();
    s[t] += v;
    __syncthreads();
  }
  if (t == 0) off[0] = 0;
  off[t + 1] = s[t];
}

// ------------------------------------------------------------------- K1: prep
__global__ void k_prep(const float* __restrict__ Wih_f, const float* __restrict__ Wih_b,
                       const float* __restrict__ bih_f, const float* __restrict__ bhh_f,
                       const float* __restrict__ bih_b, const float* __restrict__ bhh_b,
                       const float* __restrict__ Wm,
                       unsigned short* __restrict__ Wcat_hi, unsigned short* __restrict__ Wcat_lo,
                       float* __restrict__ biasA,
                       unsigned short* __restrict__ Wm_hi, unsigned short* __restrict__ Wm_lo) {
  int idx = blockIdx.x * 256 + threadIdx.x;
  int stride = gridDim.x * 256;
  for (int i = idx; i < 384 * 128; i += stride) {
    int r = i >> 7, c = i & 127;
    float v = (r < 192) ? Wih_f[r * 128 + c] : Wih_b[(r - 192) * 128 + c];
    unsigned short hi, lo;
    f2bf2(v, hi, lo);
    Wcat_hi[i] = hi;
    Wcat_lo[i] = lo;
  }
  for (int i = idx; i < 128 * 128; i += stride) {
    unsigned short hi, lo;
    f2bf2(Wm[i], hi, lo);
    Wm_hi[i] = hi;
    Wm_lo[i] = lo;
  }
  for (int i = idx; i < 384; i += stride) {
    int d = i / 192, j = i % 192;
    const float* bi = d ? bih_b : bih_f;
    const float* bh = d ? bhh_b : bhh_f;
    // r,z gates: fold bih+bhh into gx; n gate: bih only (bhh_n goes inside r*(...))
    biasA[i] = bi[j] + ((j < 128) ? bh[j] : 0.f);
  }
}

// ---------------------------------------------------------------- K2: gx GEMM
// gx[row][384]; rows = tokens; cols 0..191 fwd gates, 192..383 bwd gates.
__global__ __launch_bounds__(256) void k_gemm_gx(
    const float* __restrict__ x, const unsigned short* __restrict__ Bhi,
    const unsigned short* __restrict__ Blo, const float* __restrict__ biasA,
    float* __restrict__ gx, int total) {
  __shared__ unsigned short Ahi[64][136];
  __shared__ unsigned short Alo[64][136];
  const int tid = threadIdx.x;
  const int base = blockIdx.x * 64;
  {
    int row = tid & 63, cc = tid >> 6;
    int grow = base + row;
    if (grow >= total) grow = total - 1;
    const float* src = x + (size_t)grow * 128 + cc * 32;
#pragma unroll
    for (int u = 0; u < 8; ++u) {
      f32x4 v = *(const f32x4*)(src + u * 4);
#pragma unroll
      for (int e = 0; e < 4; ++e) {
        unsigned short h_, l_;
        f2bf2(v[e], h_, l_);
        Ahi[row][cc * 32 + u * 4 + e] = h_;
        Alo[row][cc * 32 + u * 4 + e] = l_;
      }
    }
  }
  __syncthreads();
  const int w = tid >> 6, l = tid & 63;
  const int lr = l & 15, lg = l >> 4;
  short8 afh[4], afl[4];
#pragma unroll
  for (int kc = 0; kc < 4; ++kc) {
    afh[kc] = *(const short8*)&Ahi[w * 16 + lr][kc * 32 + lg * 8];
    afl[kc] = *(const short8*)&Alo[w * 16 + lr][kc * 32 + lg * 8];
  }
#pragma unroll 1
  for (int nt = 0; nt < 24; ++nt) {
    const int ncol = nt * 16 + lr;
    const float bias = biasA[ncol];
    f32x4 acc = {bias, bias, bias, bias};
#pragma unroll
    for (int kc = 0; kc < 4; ++kc) {
      short8 bh = *(const short8*)(Bhi + (size_t)ncol * 128 + kc * 32 + lg * 8);
      short8 bl = *(const short8*)(Blo + (size_t)ncol * 128 + kc * 32 + lg * 8);
      acc = mfma16(afh[kc], bh, acc);
      acc = mfma16(afl[kc], bh, acc);
      acc = mfma16(afh[kc], bl, acc);
    }
#pragma unroll
    for (int q = 0; q < 4; ++q) {
      int row = base + w * 16 + lg * 4 + q;
      if (row < total) gx[(size_t)row * 384 + ncol] = acc[q];
    }
  }
}

// ------------------------------------------------------------------- K3: scan
// 64 wgs: wg = (seqblock<<1)|dir ; 16 seqs per wg as MFMA N-dim.
// 4 waves: wave w owns output rows j in [16w,16w+16) for all 3 gates.
__global__ __launch_bounds__(256) void k_scan(
    const float* __restrict__ gx, const int* __restrict__ off,
    const int* __restrict__ seqlens, const float* __restrict__ Whh_f,
    const float* __restrict__ Whh_b, const float* __restrict__ bhh_f,
    const float* __restrict__ bhh_b, float* __restrict__ hs) {
  // h double buffer: [buf][hilo][kc][b][40] bf16  (32 data + 8 pad per row)
  __shared__ unsigned short hbuf[2][2][2][16][40];
  const int wg = blockIdx.x;
  const int dir = wg & 1;
  const int sblk = wg >> 1;
  const int tid = threadIdx.x;
  const int w = tid >> 6, l = tid & 63;
  const int b16 = l & 15, lg = l >> 4;
  const int seq = sblk * 16 + b16;
  const int len = seqlens[seq];
  const int start = off[seq];
  const float* Whh = dir ? Whh_b : Whh_f;
  const float* bhh = dir ? bhh_b : bhh_f;
  const int dirbase = dir * 192;
  const int j0 = w * 16 + lg * 4;

  // A-fragments of Whh (hi/lo), 3 gates x 2 k-chunks
  short8 Ah[3][2], Al[3][2];
#pragma unroll
  for (int g = 0; g < 3; ++g) {
#pragma unroll
    for (int kc = 0; kc < 2; ++kc) {
      const float* wp = Whh + (size_t)(g * 64 + w * 16 + b16) * 64 + kc * 32 + lg * 8;
      f32x4 v0 = *(const f32x4*)wp;
      f32x4 v1 = *(const f32x4*)(wp + 4);
      short8 hh, ll;
#pragma unroll
      for (int e = 0; e < 4; ++e) {
        unsigned short h_, l_;
        f2bf2(v0[e], h_, l_);
        hh[e] = (short)h_;
        ll[e] = (short)l_;
      }
#pragma unroll
      for (int e = 0; e < 4; ++e) {
        unsigned short h_, l_;
        f2bf2(v1[e], h_, l_);
        hh[4 + e] = (short)h_;
        ll[4 + e] = (short)l_;
      }
      Ah[g][kc] = hh;
      Al[g][kc] = ll;
    }
  }
  const f32x4 bhhN = *(const f32x4*)(bhh + 128 + j0);

  // max length across the 16 seqs of this block (b repeats per lg group)
  int ml = len;
#pragma unroll
  for (int m = 1; m < 16; m <<= 1) ml = max(ml, __shfl_xor(ml, m, 64));

  // zero h buffer 0 (each wave covers its own write slots)
  const int kcW = w >> 1;
  const int koffW = (w & 1) * 16 + lg * 4;
  {
    uint2 z2;
    z2.x = 0u; z2.y = 0u;
    *(uint2*)&hbuf[0][0][kcW][b16][koffW] = z2;
    *(uint2*)&hbuf[0][1][kcW][b16][koffW] = z2;
  }
  f32x4 h = {0.f, 0.f, 0.f, 0.f};
  __syncthreads();

  // prefetch gx for t=0
  f32x4 gxr, gxz, gxn;
  {
    int tc = 0 < len ? 0 : len - 1;  // == 0
    int p = dir ? (len - 1 - tc) : tc;
    const float* gp = gx + (size_t)(start + p) * 384 + dirbase + j0;
    gxr = *(const f32x4*)gp;
    gxz = *(const f32x4*)(gp + 64);
    gxn = *(const f32x4*)(gp + 128);
  }

  for (int t = 0; t < ml; ++t) {
    // prefetch next step's gx (clamped)
    f32x4 ngr, ngz, ngn;
    {
      int tn = (t + 1 < ml) ? (t + 1) : (ml - 1);
      int tc = (tn < len) ? tn : (len - 1);
      int p = dir ? (len - 1 - tc) : tc;
      const float* gp = gx + (size_t)(start + p) * 384 + dirbase + j0;
      ngr = *(const f32x4*)gp;
      ngz = *(const f32x4*)(gp + 64);
      ngn = *(const f32x4*)(gp + 128);
    }
    // read h fragments (buf t&1)
    const int cb = t & 1;
    short8 bhf0 = *(const short8*)&hbuf[cb][0][0][b16][lg * 8];
    short8 bhf1 = *(const short8*)&hbuf[cb][0][1][b16][lg * 8];
    short8 blf0 = *(const short8*)&hbuf[cb][1][0][b16][lg * 8];
    short8 blf1 = *(const short8*)&hbuf[cb][1][1][b16][lg * 8];

    f32x4 ar = gxr, az = gxz, an = bhhN;
    // kc 0
    ar = mfma16(Ah[0][0], bhf0, ar);
    az = mfma16(Ah[1][0], bhf0, az);
    an = mfma16(Ah[2][0], bhf0, an);
    ar = mfma16(Ah[0][0], blf0, ar);
    az = mfma16(Ah[1][0], blf0, az);
    an = mfma16(Ah[2][0], blf0, an);
    ar = mfma16(Al[0][0], bhf0, ar);
    az = mfma16(Al[1][0], bhf0, az);
    an = mfma16(Al[2][0], bhf0, an);
    // kc 1
    ar = mfma16(Ah[0][1], bhf1, ar);
    az = mfma16(Ah[1][1], bhf1, az);
    an = mfma16(Ah[2][1], bhf1, an);
    ar = mfma16(Ah[0][1], blf1, ar);
    az = mfma16(Ah[1][1], blf1, az);
    an = mfma16(Ah[2][1], blf1, an);
    ar = mfma16(Al[0][1], bhf1, ar);
    az = mfma16(Al[1][1], bhf1, az);
    an = mfma16(Al[2][1], bhf1, an);

    // gates + state update
    f32x4 hn;
#pragma unroll
    for (int q = 0; q < 4; ++q) {
      float r = sigm(ar[q]);
      float z = sigm(az[q]);
      float npre = gxn[q] + r * an[q];
      float n = tanhft(npre);
      hn[q] = z * (h[q] - n) + n;  // (1-z)*n + z*h
    }
    const bool valid = (t < len);
    if (valid) h = hn;

    // store output state for this token
    if (valid) {
      int p = dir ? (len - 1 - t) : t;
      *(f32x4*)(hs + (size_t)(start + p) * 128 + dir * 64 + j0) = h;
    }

    // write h (hi/lo bf16) into next buffer
    {
      unsigned short h0, h1, h2, h3, l0, l1, l2, l3;
      f2bf2(h[0], h0, l0);
      f2bf2(h[1], h1, l1);
      f2bf2(h[2], h2, l2);
      f2bf2(h[3], h3, l3);
      uint2 whi, wlo;
      whi.x = pack2(h0, h1);
      whi.y = pack2(h2, h3);
      wlo.x = pack2(l0, l1);
      wlo.y = pack2(l2, l3);
      const int nb = (t + 1) & 1;
      *(uint2*)&hbuf[nb][0][kcW][b16][koffW] = whi;
      *(uint2*)&hbuf[nb][1][kcW][b16][koffW] = wlo;
    }
    gxr = ngr;
    gxz = ngz;
    gxn = ngn;
    __syncthreads();
  }
}

// --------------------------------------------------------------- K4: MLP GEMM
__global__ __launch_bounds__(256) void k_gemm_mlp(
    const float* __restrict__ hs, const unsigned short* __restrict__ Bhi,
    const unsigned short* __restrict__ Blo, const float* __restrict__ bm,
    const float* __restrict__ ctx, float* __restrict__ mlp,
    float* __restrict__ scores, int total) {
  __shared__ unsigned short Ahi[64][136];
  __shared__ unsigned short Alo[64][136];
  const int tid = threadIdx.x;
  const int base = blockIdx.x * 64;
  {
    int row = tid & 63, cc = tid >> 6;
    int grow = base + row;
    if (grow >= total) grow = total - 1;
    const float* src = hs + (size_t)grow * 128 + cc * 32;
#pragma unroll
    for (int u = 0; u < 8; ++u) {
      f32x4 v = *(const f32x4*)(src + u * 4);
#pragma unroll
      for (int e = 0; e < 4; ++e) {
        unsigned short h_, l_;
        f2bf2(v[e], h_, l_);
        Ahi[row][cc * 32 + u * 4 + e] = h_;
        Alo[row][cc * 32 + u * 4 + e] = l_;
      }
    }
  }
  __syncthreads();
  const int w = tid >> 6, l = tid & 63;
  const int lr = l & 15, lg = l >> 4;
  short8 afh[4], afl[4];
#pragma unroll
  for (int kc = 0; kc < 4; ++kc) {
    afh[kc] = *(const short8*)&Ahi[w * 16 + lr][kc * 32 + lg * 8];
    afl[kc] = *(const short8*)&Alo[w * 16 + lr][kc * 32 + lg * 8];
  }
  float sc0 = 0.f, sc1 = 0.f, sc2 = 0.f, sc3 = 0.f;
#pragma unroll 1
  for (int nt = 0; nt < 8; ++nt) {
    const int ncol = nt * 16 + lr;
    const float bias = bm[ncol];
    const float cv = ctx[ncol];
    f32x4 acc = {bias, bias, bias, bias};
#pragma unroll
    for (int kc = 0; kc < 4; ++kc) {
      short8 bh = *(const short8*)(Bhi + (size_t)ncol * 128 + kc * 32 + lg * 8);
      short8 bl = *(const short8*)(Blo + (size_t)ncol * 128 + kc * 32 + lg * 8);
      acc = mfma16(afh[kc], bh, acc);
      acc = mfma16(afl[kc], bh, acc);
      acc = mfma16(afh[kc], bl, acc);
    }
    const int r0 = base + w * 16 + lg * 4;
    float tv0 = tanhft(acc[0]);
    float tv1 = tanhft(acc[1]);
    float tv2 = tanhft(acc[2]);
    float tv3 = tanhft(acc[3]);
    if (r0 + 0 < total) mlp[(size_t)(r0 + 0) * 128 + ncol] = tv0;
    if (r0 + 1 < total) mlp[(size_t)(r0 + 1) * 128 + ncol] = tv1;
    if (r0 + 2 < total) mlp[(size_t)(r0 + 2) * 128 + ncol] = tv2;
    if (r0 + 3 < total) mlp[(size_t)(r0 + 3) * 128 + ncol] = tv3;
    sc0 += tv0 * cv;
    sc1 += tv1 * cv;
    sc2 += tv2 * cv;
    sc3 += tv3 * cv;
  }
#pragma unroll
  for (int m = 1; m < 16; m <<= 1) {
    sc0 += __shfl_xor(sc0, m, 64);
    sc1 += __shfl_xor(sc1, m, 64);
    sc2 += __shfl_xor(sc2, m, 64);
    sc3 += __shfl_xor(sc3, m, 64);
  }
  if (lr == 0) {
    const int r0 = base + w * 16 + lg * 4;
    if (r0 + 0 < total) scores[r0 + 0] = sc0;
    if (r0 + 1 < total) scores[r0 + 1] = sc1;
    if (r0 + 2 < total) scores[r0 + 2] = sc2;
    if (r0 + 3 < total) scores[r0 + 3] = sc3;
  }
}

// ------------------------------------------------------------------- K5: pool
__global__ __launch_bounds__(128) void k_pool(
    const float* __restrict__ scores, const float* __restrict__ mlp,
    const int* __restrict__ off, const int* __restrict__ seqlens,
    float* __restrict__ out) {
  const int s = blockIdx.x;
  const int tid = threadIdx.x;
  const int len = seqlens[s];
  const int st = off[s];
  // pass 1: max
  float m = -1e30f;
  for (int t = tid; t < len; t += 128) m = fmaxf(m, scores[st + t]);
#pragma unroll
  for (int d = 1; d < 64; d <<= 1) m = fmaxf(m, __shfl_xor(m, d, 64));
  __shared__ float wm[2];
  if ((tid & 63) == 0) wm[tid >> 6] = m;
  __syncthreads();
  m = fmaxf(wm[0], wm[1]);
  // pass 2: weighted sum (each thread owns one output column)
  float acc = 0.f, wsum = 0.f;
  for (int t = 0; t < len; ++t) {
    float wv = __expf(scores[st + t] - m);
    wsum += wv;
    acc += wv * mlp[(size_t)(st + t) * 128 + tid];
  }
  out[(size_t)s * 128 + tid] = acc / wsum;
}

// ---------------------------------------------------------------------- launch
extern "C" void kernel_launch(void* const* d_in, const int* in_sizes, int n_in,
                              void* d_out, int out_size, void* d_ws, size_t ws_size,
                              hipStream_t stream) {
  const float* seqs = (const float*)d_in[0];
  const int* seqlens = (const int*)d_in[1];
  const float* Wih_f = (const float*)d_in[2];
  const float* Whh_f = (const float*)d_in[3];
  const float* bih_f = (const float*)d_in[4];
  const float* bhh_f = (const float*)d_in[5];
  const float* Wih_b = (const float*)d_in[6];
  const float* Whh_b = (const float*)d_in[7];
  const float* bih_b = (const float*)d_in[8];
  const float* bhh_b = (const float*)d_in[9];
  const float* Wm = (const float*)d_in[10];
  const float* bm = (const float*)d_in[11];
  const float* ctx = (const float*)d_in[12];

  const int total = in_sizes[0] / 128;

  char* ws = (char*)d_ws;
  size_t o = 0;
  auto alloc = [&](size_t bytes) {
    size_t r = o;
    o = (o + bytes + 255) & ~(size_t)255;
    return r;
  };
  int* off = (int*)(ws + alloc(513 * 4));
  unsigned short* Wcat_hi = (unsigned short*)(ws + alloc(384 * 128 * 2));
  unsigned short* Wcat_lo = (unsigned short*)(ws + alloc(384 * 128 * 2));
  float* biasA = (float*)(ws + alloc(384 * 4));
  unsigned short* Wm_hi = (unsigned short*)(ws + alloc(128 * 128 * 2));
  unsigned short* Wm_lo = (unsigned short*)(ws + alloc(128 * 128 * 2));
  float* scores = (float*)(ws + alloc((size_t)total * 4));
  float* gxbuf = (float*)(ws + alloc((size_t)total * 384 * 4));
  float* hsbuf = (float*)(ws + alloc((size_t)total * 128 * 4));
  float* mlp = gxbuf;  // reuse gx region after the scan

  k_offsets<<<1, 512, 0, stream>>>(seqlens, off);
  k_prep<<<64, 256, 0, stream>>>(Wih_f, Wih_b, bih_f, bhh_f, bih_b, bhh_b, Wm,
                                 Wcat_hi, Wcat_lo, biasA, Wm_hi, Wm_lo);
  const int mt = (total + 63) / 64;
  k_gemm_gx<<<mt, 256, 0, stream>>>(seqs, Wcat_hi, Wcat_lo, biasA, gxbuf, total);
  k_scan<<<64, 256, 0, stream>>>(gxbuf, off, seqlens, Whh_f, Whh_b, bhh_f, bhh_b, hsbuf);
  k_gemm_mlp<<<mt, 256, 0, stream>>>(hsbuf, Wm_hi, Wm_lo, bm, ctx, mlp, scores, total);
  k_pool<<<512, 128, 0, stream>>>(scores, mlp, off, seqlens, (float*)d_out);
}

// Round 2
// 898.077 us; speedup vs baseline: 1.0775x; 1.0775x over previous
//
#include <hip/hip_runtime.h>
#include <hip/hip_bf16.h>
#include <stdint.h>

// ---------------------------------------------------------------------------
// AttendedSeqEmbedding: ragged bidirectional GRU + MLP + attention pooling
// I=128, H=64, O=128, B=512, T<=512
//   K0 offsets   : prefix-sum of seqlens
//   K1 prep      : f32 -> bf16 hi/lo weight splits, fused gate biases
//   K2 gemm_gx   : gx[tok][384] = x @ [Wih_f;Wih_b]^T + biases (MFMA hi/lo)
//   K3 scan      : 1024 scans batched 16-wide as MFMA N-dim, h in LDS dbuf
//                  raw s_barrier + lgkmcnt-only wait (no vmcnt(0) drain),
//                  2-step-ahead gx prefetch with register rotation
//   K4 gemm_mlp  : mlp[tok][128] = tanh(hs @ Wm^T + bm), scores = mlp . ctx
//   K5 pool      : per-seq softmax(scores) weighted sum, 4 t-slices/block
// ---------------------------------------------------------------------------

typedef __attribute__((ext_vector_type(8))) short short8;
typedef __attribute__((ext_vector_type(4))) float f32x4;

__device__ __forceinline__ unsigned short f2bf(float f) {
  unsigned int u = __float_as_uint(f);
  u = (u + 0x7FFFu + ((u >> 16) & 1u)) >> 16;
  return (unsigned short)u;
}
__device__ __forceinline__ float bf2f(unsigned short h) {
  return __uint_as_float(((unsigned int)h) << 16);
}
__device__ __forceinline__ void f2bf2(float f, unsigned short& hi, unsigned short& lo) {
  hi = f2bf(f);
  lo = f2bf(f - bf2f(hi));
}
__device__ __forceinline__ f32x4 mfma16(short8 a, short8 b, f32x4 c) {
  return __builtin_amdgcn_mfma_f32_16x16x32_bf16(a, b, c, 0, 0, 0);
}
__device__ __forceinline__ float rcpf(float x) { return __builtin_amdgcn_rcpf(x); }
__device__ __forceinline__ float sigm(float x) { return rcpf(1.f + __expf(-x)); }
__device__ __forceinline__ float tanhft(float x) {
  float e = __expf(2.f * x);
  return 1.f - 2.f * rcpf(e + 1.f);
}
__device__ __forceinline__ unsigned int pack2(unsigned short a, unsigned short b) {
  return (unsigned int)a | ((unsigned int)b << 16);
}
// lgkm-only barrier: global loads/stores stay in flight (no vmcnt(0) drain)
__device__ __forceinline__ void lds_barrier() {
  __builtin_amdgcn_sched_barrier(0);
  asm volatile("s_waitcnt lgkmcnt(0)");
  __builtin_amdgcn_s_barrier();
  __builtin_amdgcn_sched_barrier(0);
}

// ---------------------------------------------------------------- K0: offsets
__global__ void k_offsets(const int* __restrict__ seqlens, int* __restrict__ off) {
  __shared__ int s[512];
  int t = threadIdx.x;
  s[t] = seqlens[t];
  __syncthreads();
  for (int d = 1; d < 512; d <<= 1) {
    int v = (t >= d) ? s[t - d] : 0;
    __syncthreads();
    s[t] += v;
    __syncthreads();
  }
  if (t == 0) off[0] = 0;
  off[t + 1] = s[t];
}

// ------------------------------------------------------------------- K1: prep
__global__ void k_prep(const float* __restrict__ Wih_f, const float* __restrict__ Wih_b,
                       const float* __restrict__ bih_f, const float* __restrict__ bhh_f,
                       const float* __restrict__ bih_b, const float* __restrict__ bhh_b,
                       const float* __restrict__ Wm,
                       unsigned short* __restrict__ Wcat_hi, unsigned short* __restrict__ Wcat_lo,
                       float* __restrict__ biasA,
                       unsigned short* __restrict__ Wm_hi, unsigned short* __restrict__ Wm_lo) {
  int idx = blockIdx.x * 256 + threadIdx.x;
  int stride = gridDim.x * 256;
  for (int i = idx; i < 384 * 128; i += stride) {
    int r = i >> 7, c = i & 127;
    float v = (r < 192) ? Wih_f[r * 128 + c] : Wih_b[(r - 192) * 128 + c];
    unsigned short hi, lo;
    f2bf2(v, hi, lo);
    Wcat_hi[i] = hi;
    Wcat_lo[i] = lo;
  }
  for (int i = idx; i < 128 * 128; i += stride) {
    unsigned short hi, lo;
    f2bf2(Wm[i], hi, lo);
    Wm_hi[i] = hi;
    Wm_lo[i] = lo;
  }
  for (int i = idx; i < 384; i += stride) {
    int d = i / 192, j = i % 192;
    const float* bi = d ? bih_b : bih_f;
    const float* bh = d ? bhh_b : bhh_f;
    biasA[i] = bi[j] + ((j < 128) ? bh[j] : 0.f);
  }
}

// ---------------------------------------------------------------- K2: gx GEMM
__global__ __launch_bounds__(256) void k_gemm_gx(
    const float* __restrict__ x, const unsigned short* __restrict__ Bhi,
    const unsigned short* __restrict__ Blo, const float* __restrict__ biasA,
    float* __restrict__ gx, int total) {
  __shared__ unsigned short Ahi[64][136];
  __shared__ unsigned short Alo[64][136];
  const int tid = threadIdx.x;
  const int base = blockIdx.x * 64;
  {
    int row = tid & 63, cc = tid >> 6;
    int grow = base + row;
    if (grow >= total) grow = total - 1;
    const float* src = x + (size_t)grow * 128 + cc * 32;
#pragma unroll
    for (int u = 0; u < 8; ++u) {
      f32x4 v = *(const f32x4*)(src + u * 4);
#pragma unroll
      for (int e = 0; e < 4; ++e) {
        unsigned short h_, l_;
        f2bf2(v[e], h_, l_);
        Ahi[row][cc * 32 + u * 4 + e] = h_;
        Alo[row][cc * 32 + u * 4 + e] = l_;
      }
    }
  }
  __syncthreads();
  const int w = tid >> 6, l = tid & 63;
  const int lr = l & 15, lg = l >> 4;
  short8 afh[4], afl[4];
#pragma unroll
  for (int kc = 0; kc < 4; ++kc) {
    afh[kc] = *(const short8*)&Ahi[w * 16 + lr][kc * 32 + lg * 8];
    afl[kc] = *(const short8*)&Alo[w * 16 + lr][kc * 32 + lg * 8];
  }
#pragma unroll 1
  for (int nt = 0; nt < 24; ++nt) {
    const int ncol = nt * 16 + lr;
    const float bias = biasA[ncol];
    f32x4 acc = {bias, bias, bias, bias};
#pragma unroll
    for (int kc = 0; kc < 4; ++kc) {
      short8 bh = *(const short8*)(Bhi + (size_t)ncol * 128 + kc * 32 + lg * 8);
      short8 bl = *(const short8*)(Blo + (size_t)ncol * 128 + kc * 32 + lg * 8);
      acc = mfma16(afh[kc], bh, acc);
      acc = mfma16(afl[kc], bh, acc);
      acc = mfma16(afh[kc], bl, acc);
    }
#pragma unroll
    for (int q = 0; q < 4; ++q) {
      int row = base + w * 16 + lg * 4 + q;
      if (row < total) gx[(size_t)row * 384 + ncol] = acc[q];
    }
  }
}

// ------------------------------------------------------------------- K3: scan
__global__ __launch_bounds__(256) void k_scan(
    const float* __restrict__ gx, const int* __restrict__ off,
    const int* __restrict__ seqlens, const float* __restrict__ Whh_f,
    const float* __restrict__ Whh_b, const float* __restrict__ bhh_f,
    const float* __restrict__ bhh_b, float* __restrict__ hs) {
  __shared__ unsigned short hbuf[2][2][2][16][40];
  const int wg = blockIdx.x;
  const int dir = wg & 1;
  const int sblk = wg >> 1;
  const int tid = threadIdx.x;
  const int w = tid >> 6, l = tid & 63;
  const int b16 = l & 15, lg = l >> 4;
  const int seq = sblk * 16 + b16;
  const int len = seqlens[seq];
  const int start = off[seq];
  const float* Whh = dir ? Whh_b : Whh_f;
  const float* bhh = dir ? bhh_b : bhh_f;
  const int dirbase = dir * 192;
  const int j0 = w * 16 + lg * 4;

  short8 Ah[3][2], Al[3][2];
#pragma unroll
  for (int g = 0; g < 3; ++g) {
#pragma unroll
    for (int kc = 0; kc < 2; ++kc) {
      const float* wp = Whh + (size_t)(g * 64 + w * 16 + b16) * 64 + kc * 32 + lg * 8;
      f32x4 v0 = *(const f32x4*)wp;
      f32x4 v1 = *(const f32x4*)(wp + 4);
      short8 hh, ll;
#pragma unroll
      for (int e = 0; e < 4; ++e) {
        unsigned short h_, l_;
        f2bf2(v0[e], h_, l_);
        hh[e] = (short)h_;
        ll[e] = (short)l_;
      }
#pragma unroll
      for (int e = 0; e < 4; ++e) {
        unsigned short h_, l_;
        f2bf2(v1[e], h_, l_);
        hh[4 + e] = (short)h_;
        ll[4 + e] = (short)l_;
      }
      Ah[g][kc] = hh;
      Al[g][kc] = ll;
    }
  }
  const f32x4 bhhN = *(const f32x4*)(bhh + 128 + j0);

  int ml = len;
#pragma unroll
  for (int m = 1; m < 16; m <<= 1) ml = max(ml, __shfl_xor(ml, m, 64));

  const int kcW = w >> 1;
  const int koffW = (w & 1) * 16 + lg * 4;
  {
    uint2 z2;
    z2.x = 0u; z2.y = 0u;
    *(uint2*)&hbuf[0][0][kcW][b16][koffW] = z2;
    *(uint2*)&hbuf[0][1][kcW][b16][koffW] = z2;
  }
  f32x4 h = {0.f, 0.f, 0.f, 0.f};
  lds_barrier();

  const int p0 = dir ? (len - 1) : 0;
  const float* gp = gx + (size_t)(start + p0) * 384 + dirbase + j0;
  float* hp = hs + (size_t)(start + p0) * 128 + dir * 64 + j0;
  const ptrdiff_t gstep = dir ? -384 : 384;
  const ptrdiff_t hstep = dir ? -128 : 128;

  f32x4 g0r = *(const f32x4*)gp;
  f32x4 g0z = *(const f32x4*)(gp + 64);
  f32x4 g0n = *(const f32x4*)(gp + 128);
  if (1 < len) gp += gstep;
  f32x4 g1r = *(const f32x4*)gp;
  f32x4 g1z = *(const f32x4*)(gp + 64);
  f32x4 g1n = *(const f32x4*)(gp + 128);
  if (2 < len) gp += gstep;

#pragma unroll 2
  for (int t = 0; t < ml; ++t) {
    f32x4 g2r = *(const f32x4*)gp;
    f32x4 g2z = *(const f32x4*)(gp + 64);
    f32x4 g2n = *(const f32x4*)(gp + 128);
    if (t + 4 <= len) gp += gstep;

    const int cb = t & 1;
    short8 bhf0 = *(const short8*)&hbuf[cb][0][0][b16][lg * 8];
    short8 bhf1 = *(const short8*)&hbuf[cb][0][1][b16][lg * 8];
    short8 blf0 = *(const short8*)&hbuf[cb][1][0][b16][lg * 8];
    short8 blf1 = *(const short8*)&hbuf[cb][1][1][b16][lg * 8];

    f32x4 ar = g0r, az = g0z, an = bhhN;
    ar = mfma16(Ah[0][0], bhf0, ar);
    az = mfma16(Ah[1][0], bhf0, az);
    an = mfma16(Ah[2][0], bhf0, an);
    ar = mfma16(Ah[0][0], blf0, ar);
    az = mfma16(Ah[1][0], blf0, az);
    an = mfma16(Ah[2][0], blf0, an);
    ar = mfma16(Al[0][0], bhf0, ar);
    az = mfma16(Al[1][0], bhf0, az);
    an = mfma16(Al[2][0], bhf0, an);
    ar = mfma16(Ah[0][1], bhf1, ar);
    az = mfma16(Ah[1][1], bhf1, az);
    an = mfma16(Ah[2][1], bhf1, an);
    ar = mfma16(Ah[0][1], blf1, ar);
    az = mfma16(Ah[1][1], blf1, az);
    an = mfma16(Ah[2][1], blf1, an);
    ar = mfma16(Al[0][1], bhf1, ar);
    az = mfma16(Al[1][1], bhf1, az);
    an = mfma16(Al[2][1], bhf1, an);

    f32x4 hn;
#pragma unroll
    for (int q = 0; q < 4; ++q) {
      float r = sigm(ar[q]);
      float z = sigm(az[q]);
      float n = tanhft(g0n[q] + r * an[q]);
      hn[q] = z * (h[q] - n) + n;
    }
    const bool valid = (t < len);
    if (valid) {
      h = hn;
      *(f32x4*)hp = h;
      if (t + 1 < len) hp += hstep;
    }

    {
      unsigned short h0, h1, h2, h3, l0, l1, l2, l3;
      f2bf2(h[0], h0, l0);
      f2bf2(h[1], h1, l1);
      f2bf2(h[2], h2, l2);
      f2bf2(h[3], h3, l3);
      uint2 whi, wlo;
      whi.x = pack2(h0, h1);
      whi.y = pack2(h2, h3);
      wlo.x = pack2(l0, l1);
      wlo.y = pack2(l2, l3);
      const int nb = (t + 1) & 1;
      *(uint2*)&hbuf[nb][0][kcW][b16][koffW] = whi;
      *(uint2*)&hbuf[nb][1][kcW][b16][koffW] = wlo;
    }
    lds_barrier();
    g0r = g1r; g0z = g1z; g0n = g1n;
    g1r = g2r; g1z = g2z; g1n = g2n;
  }
}

// --------------------------------------------------------------- K4: MLP GEMM
__global__ __launch_bounds__(256) void k_gemm_mlp(
    const float* __restrict__ hs, const unsigned short* __restrict__ Bhi,
    const unsigned short* __restrict__ Blo, const float* __restrict__ bm,
    const float* __restrict__ ctx, float* __restrict__ mlp,
    float* __restrict__ scores, int total) {
  __shared__ unsigned short Ahi[64][136];
  __shared__ unsigned short Alo[64][136];
  const int tid = threadIdx.x;
  const int base = blockIdx.x * 64;
  {
    int row = tid & 63, cc = tid >> 6;
    int grow = base + row;
    if (grow >= total) grow = total - 1;
    const float* src = hs + (size_t)grow * 128 + cc * 32;
#pragma unroll
    for (int u = 0; u < 8; ++u) {
      f32x4 v = *(const f32x4*)(src + u * 4);
#pragma unroll
      for (int e = 0; e < 4; ++e) {
        unsigned short h_, l_;
        f2bf2(v[e], h_, l_);
        Ahi[row][cc * 32 + u * 4 + e] = h_;
        Alo[row][cc * 32 + u * 4 + e] = l_;
      }
    }
  }
  __syncthreads();
  const int w = tid >> 6, l = tid & 63;
  const int lr = l & 15, lg = l >> 4;
  short8 afh[4], afl[4];
#pragma unroll
  for (int kc = 0; kc < 4; ++kc) {
    afh[kc] = *(const short8*)&Ahi[w * 16 + lr][kc * 32 + lg * 8];
    afl[kc] = *(const short8*)&Alo[w * 16 + lr][kc * 32 + lg * 8];
  }
  float sc0 = 0.f, sc1 = 0.f, sc2 = 0.f, sc3 = 0.f;
#pragma unroll 1
  for (int nt = 0; nt < 8; ++nt) {
    const int ncol = nt * 16 + lr;
    const float bias = bm[ncol];
    const float cv = ctx[ncol];
    f32x4 acc = {bias, bias, bias, bias};
#pragma unroll
    for (int kc = 0; kc < 4; ++kc) {
      short8 bh = *(const short8*)(Bhi + (size_t)ncol * 128 + kc * 32 + lg * 8);
      short8 bl = *(const short8*)(Blo + (size_t)ncol * 128 + kc * 32 + lg * 8);
      acc = mfma16(afh[kc], bh, acc);
      acc = mfma16(afl[kc], bh, acc);
      acc = mfma16(afh[kc], bl, acc);
    }
    const int r0 = base + w * 16 + lg * 4;
    float tv0 = tanhft(acc[0]);
    float tv1 = tanhft(acc[1]);
    float tv2 = tanhft(acc[2]);
    float tv3 = tanhft(acc[3]);
    if (r0 + 0 < total) mlp[(size_t)(r0 + 0) * 128 + ncol] = tv0;
    if (r0 + 1 < total) mlp[(size_t)(r0 + 1) * 128 + ncol] = tv1;
    if (r0 + 2 < total) mlp[(size_t)(r0 + 2) * 128 + ncol] = tv2;
    if (r0 + 3 < total) mlp[(size_t)(r0 + 3) * 128 + ncol] = tv3;
    sc0 += tv0 * cv;
    sc1 += tv1 * cv;
    sc2 += tv2 * cv;
    sc3 += tv3 * cv;
  }
#pragma unroll
  for (int m = 1; m < 16; m <<= 1) {
    sc0 += __shfl_xor(sc0, m, 64);
    sc1 += __shfl_xor(sc1, m, 64);
    sc2 += __shfl_xor(sc2, m, 64);
    sc3 += __shfl_xor(sc3, m, 64);
  }
  if (lr == 0) {
    const int r0 = base + w * 16 + lg * 4;
    if (r0 + 0 < total) scores[r0 + 0] = sc0;
    if (r0 + 1 < total) scores[r0 + 1] = sc1;
    if (r0 + 2 < total) scores[r0 + 2] = sc2;
    if (r0 + 3 < total) scores[r0 + 3] = sc3;
  }
}

// ------------------------------------------------------------------- K5: pool
__global__ __launch_bounds__(512) void k_pool(
    const float* __restrict__ scores, const float* __restrict__ mlp,
    const int* __restrict__ off, const int* __restrict__ seqlens,
    float* __restrict__ out) {
  const int s = blockIdx.x;
  const int tid = threadIdx.x;
  const int len = seqlens[s];
  const int st = off[s];
  const int col = tid & 127, slice = tid >> 7;
  float m = (tid < len) ? scores[st + tid] : -1e30f;
#pragma unroll
  for (int d = 1; d < 64; d <<= 1) m = fmaxf(m, __shfl_xor(m, d, 64));
  __shared__ float wmx[8];
  if ((tid & 63) == 0) wmx[tid >> 6] = m;
  __syncthreads();
  m = wmx[0];
#pragma unroll
  for (int i = 1; i < 8; ++i) m = fmaxf(m, wmx[i]);
  float acc = 0.f, ws = 0.f;
  for (int t = slice; t < len; t += 4) {
    float wv = __expf(scores[st + t] - m);
    ws += wv;
    acc += wv * mlp[(size_t)(st + t) * 128 + col];
  }
  __shared__ float accs[4][128];
  __shared__ float wss[4];
  accs[slice][col] = acc;
  if (col == 0) wss[slice] = ws;
  __syncthreads();
  if (tid < 128) {
    float a = accs[0][tid] + accs[1][tid] + accs[2][tid] + accs[3][tid];
    float wsum = wss[0] + wss[1] + wss[2] + wss[3];
    out[(size_t)s * 128 + tid] = a * rcpf(wsum);
  }
}

// ---------------------------------------------------------------------- launch
extern "C" void kernel_launch(void* const* d_in, const int* in_sizes, int n_in,
                              void* d_out, int out_size, void* d_ws, size_t ws_size,
                              hipStream_t stream) {
  const float* seqs = (const float*)d_in[0];
  const int* seqlens = (const int*)d_in[1];
  const float* Wih_f = (const float*)d_in[2];
  const float* Whh_f = (const float*)d_in[3];
  const float* bih_f = (const float*)d_in[4];
  const float* bhh_f = (const float*)d_in[5];
  const float* Wih_b = (const float*)d_in[6];
  const float* Whh_b = (const float*)d_in[7];
  const float* bih_b = (const float*)d_in[8];
  const float* bhh_b = (const float*)d_in[9];
  const float* Wm = (const float*)d_in[10];
  const float* bm = (const float*)d_in[11];
  const float* ctx = (const float*)d_in[12];

  const int total = in_sizes[0] / 128;

  char* ws = (char*)d_ws;
  size_t o = 0;
  auto alloc = [&](size_t bytes) {
    size_t r = o;
    o = (o + bytes + 255) & ~(size_t)255;
    return r;
  };
  int* off = (int*)(ws + alloc(513 * 4));
  unsigned short* Wcat_hi = (unsigned short*)(ws + alloc(384 * 128 * 2));
  unsigned short* Wcat_lo = (unsigned short*)(ws + alloc(384 * 128 * 2));
  float* biasA = (float*)(ws + alloc(384 * 4));
  unsigned short* Wm_hi = (unsigned short*)(ws + alloc(128 * 128 * 2));
  unsigned short* Wm_lo = (unsigned short*)(ws + alloc(128 * 128 * 2));
  float* scores = (float*)(ws + alloc((size_t)total * 4));
  float* gxbuf = (float*)(ws + alloc((size_t)total * 384 * 4));
  float* hsbuf = (float*)(ws + alloc((size_t)total * 128 * 4));
  float* mlp = gxbuf;  // reuse gx region after the scan

  k_offsets<<<1, 512, 0, stream>>>(seqlens, off);
  k_prep<<<64, 256, 0, stream>>>(Wih_f, Wih_b, bih_f, bhh_f, bih_b, bhh_b, Wm,
                                 Wcat_hi, Wcat_lo, biasA, Wm_hi, Wm_lo);
  const int mt = (total + 63) / 64;
  k_gemm_gx<<<mt, 256, 0, stream>>>(seqs, Wcat_hi, Wcat_lo, biasA, gxbuf, total);
  k_scan<<<64, 256, 0, stream>>>(gxbuf, off, seqlens, Whh_f, Whh_b, bhh_f, bhh_b, hsbuf);
  k_gemm_mlp<<<mt, 256, 0, stream>>>(hsbuf, Wm_hi, Wm_lo, bm, ctx, mlp, scores, total);
  k_pool<<<512, 512, 0, stream>>>(scores, mlp, off, seqlens, (float*)d_out);
}

// Round 3
// 657.830 us; speedup vs baseline: 1.4710x; 1.3652x over previous
//
#include <hip/hip_runtime.h>
#include <hip/hip_bf16.h>
#include <stdint.h>

// ---------------------------------------------------------------------------
// AttendedSeqEmbedding: ragged bidirectional GRU + MLP + attention pooling
// I=128, H=64, O=128, B=512, T<=512
//   K0 offsets   : prefix-sum of seqlens
//   K1 prep      : f32 -> bf16 hi/lo weight splits, fused gate biases
//   K2 gemm_gx   : gx[tok][384] = x @ [Wih_f;Wih_b]^T + biases (MFMA hi/lo)
//   K3 scan      : 1024 scans batched 16-wide as MFMA N-dim, h in LDS dbuf.
//                  Static 8-deep global prefetch pipeline (all slot indices
//                  compile-time), lgkm-only barrier, launch_bounds(256,1).
//   K4 gemm_mlp  : mlp[tok][128] = tanh(hs @ Wm^T + bm), scores = mlp . ctx
//   K5 pool      : per-seq softmax(scores) weighted sum, 4 t-slices/block
// ---------------------------------------------------------------------------

typedef __attribute__((ext_vector_type(8))) short short8;
typedef __attribute__((ext_vector_type(4))) float f32x4;

__device__ __forceinline__ unsigned short f2bf(float f) {
  unsigned int u = __float_as_uint(f);
  u = (u + 0x7FFFu + ((u >> 16) & 1u)) >> 16;
  return (unsigned short)u;
}
__device__ __forceinline__ float bf2f(unsigned short h) {
  return __uint_as_float(((unsigned int)h) << 16);
}
__device__ __forceinline__ void f2bf2(float f, unsigned short& hi, unsigned short& lo) {
  hi = f2bf(f);
  lo = f2bf(f - bf2f(hi));
}
__device__ __forceinline__ f32x4 mfma16(short8 a, short8 b, f32x4 c) {
  return __builtin_amdgcn_mfma_f32_16x16x32_bf16(a, b, c, 0, 0, 0);
}
__device__ __forceinline__ float rcpf(float x) { return __builtin_amdgcn_rcpf(x); }
__device__ __forceinline__ float sigm(float x) { return rcpf(1.f + __expf(-x)); }
__device__ __forceinline__ float tanhft(float x) {
  float e = __expf(2.f * x);
  return 1.f - 2.f * rcpf(e + 1.f);
}

// ---------------------------------------------------------------- K0: offsets
__global__ void k_offsets(const int* __restrict__ seqlens, int* __restrict__ off) {
  __shared__ int s[512];
  int t = threadIdx.x;
  s[t] = seqlens[t];
  __syncthreads();
  for (int d = 1; d < 512; d <<= 1) {
    int v = (t >= d) ? s[t - d] : 0;
    __syncthreads();
    s[t] += v;
    __syncthreads();
  }
  if (t == 0) off[0] = 0;
  off[t + 1] = s[t];
}

// ------------------------------------------------------------------- K1: prep
__global__ void k_prep(const float* __restrict__ Wih_f, const float* __restrict__ Wih_b,
                       const float* __restrict__ bih_f, const float* __restrict__ bhh_f,
                       const float* __restrict__ bih_b, const float* __restrict__ bhh_b,
                       const float* __restrict__ Wm,
                       unsigned short* __restrict__ Wcat_hi, unsigned short* __restrict__ Wcat_lo,
                       float* __restrict__ biasA,
                       unsigned short* __restrict__ Wm_hi, unsigned short* __restrict__ Wm_lo) {
  int idx = blockIdx.x * 256 + threadIdx.x;
  int stride = gridDim.x * 256;
  for (int i = idx; i < 384 * 128; i += stride) {
    int r = i >> 7, c = i & 127;
    float v = (r < 192) ? Wih_f[r * 128 + c] : Wih_b[(r - 192) * 128 + c];
    unsigned short hi, lo;
    f2bf2(v, hi, lo);
    Wcat_hi[i] = hi;
    Wcat_lo[i] = lo;
  }
  for (int i = idx; i < 128 * 128; i += stride) {
    unsigned short hi, lo;
    f2bf2(Wm[i], hi, lo);
    Wm_hi[i] = hi;
    Wm_lo[i] = lo;
  }
  for (int i = idx; i < 384; i += stride) {
    int d = i / 192, j = i % 192;
    const float* bi = d ? bih_b : bih_f;
    const float* bh = d ? bhh_b : bhh_f;
    biasA[i] = bi[j] + ((j < 128) ? bh[j] : 0.f);
  }
}

// ---------------------------------------------------------------- K2: gx GEMM
__global__ __launch_bounds__(256) void k_gemm_gx(
    const float* __restrict__ x, const unsigned short* __restrict__ Bhi,
    const unsigned short* __restrict__ Blo, const float* __restrict__ biasA,
    float* __restrict__ gx, int total) {
  __shared__ unsigned short Ahi[64][136];
  __shared__ unsigned short Alo[64][136];
  const int tid = threadIdx.x;
  const int base = blockIdx.x * 64;
  {
    int row = tid & 63, cc = tid >> 6;
    int grow = base + row;
    if (grow >= total) grow = total - 1;
    const float* src = x + (size_t)grow * 128 + cc * 32;
#pragma unroll
    for (int u = 0; u < 8; ++u) {
      f32x4 v = *(const f32x4*)(src + u * 4);
#pragma unroll
      for (int e = 0; e < 4; ++e) {
        unsigned short h_, l_;
        f2bf2(v[e], h_, l_);
        Ahi[row][cc * 32 + u * 4 + e] = h_;
        Alo[row][cc * 32 + u * 4 + e] = l_;
      }
    }
  }
  __syncthreads();
  const int w = tid >> 6, l = tid & 63;
  const int lr = l & 15, lg = l >> 4;
  short8 afh[4], afl[4];
#pragma unroll
  for (int kc = 0; kc < 4; ++kc) {
    afh[kc] = *(const short8*)&Ahi[w * 16 + lr][kc * 32 + lg * 8];
    afl[kc] = *(const short8*)&Alo[w * 16 + lr][kc * 32 + lg * 8];
  }
#pragma unroll 1
  for (int nt = 0; nt < 24; ++nt) {
    const int ncol = nt * 16 + lr;
    const float bias = biasA[ncol];
    f32x4 acc = {bias, bias, bias, bias};
#pragma unroll
    for (int kc = 0; kc < 4; ++kc) {
      short8 bh = *(const short8*)(Bhi + (size_t)ncol * 128 + kc * 32 + lg * 8);
      short8 bl = *(const short8*)(Blo + (size_t)ncol * 128 + kc * 32 + lg * 8);
      acc = mfma16(afh[kc], bh, acc);
      acc = mfma16(afl[kc], bh, acc);
      acc = mfma16(afh[kc], bl, acc);
    }
#pragma unroll
    for (int q = 0; q < 4; ++q) {
      int row = base + w * 16 + lg * 4 + q;
      if (row < total) gx[(size_t)row * 384 + ncol] = acc[q];
    }
  }
}

// ------------------------------------------------------------------- K3: scan
// 64 wgs: wg = (seqblock<<1)|dir ; 16 seqs per wg as MFMA N-dim.
// 4 waves: wave w owns output rows j in [16w,16w+16) for all 3 gates.
// Static 8-deep pipeline: Gr/Gz/Gn[8] slots, loop stepped by 8 so every
// slot / LDS-buffer index is a compile-time constant.
__global__ __launch_bounds__(256, 1) void k_scan(
    const float* __restrict__ gx, const int* __restrict__ off,
    const int* __restrict__ seqlens, const float* __restrict__ Whh_f,
    const float* __restrict__ Whh_b, const float* __restrict__ bhh_f,
    const float* __restrict__ bhh_b, float* __restrict__ hs) {
  __shared__ unsigned short hbuf[2][2][2][16][40];
  const int wg = blockIdx.x;
  const int dir = wg & 1;
  const int sblk = wg >> 1;
  const int tid = threadIdx.x;
  const int w = tid >> 6, l = tid & 63;
  const int b16 = l & 15, lg = l >> 4;
  const int seq = sblk * 16 + b16;
  const int len = seqlens[seq];
  const int start = off[seq];
  const float* Whh = dir ? Whh_b : Whh_f;
  const float* bhh = dir ? bhh_b : bhh_f;
  const int dirbase = dir * 192;
  const int j0 = w * 16 + lg * 4;

  // A-fragments of Whh (hi/lo), 3 gates x 2 k-chunks
  short8 Ah[3][2], Al[3][2];
#pragma unroll
  for (int g = 0; g < 3; ++g) {
#pragma unroll
    for (int kc = 0; kc < 2; ++kc) {
      const float* wp = Whh + (size_t)(g * 64 + w * 16 + b16) * 64 + kc * 32 + lg * 8;
      f32x4 v0 = *(const f32x4*)wp;
      f32x4 v1 = *(const f32x4*)(wp + 4);
      short8 hh, ll;
#pragma unroll
      for (int e = 0; e < 4; ++e) {
        unsigned short h_, l_;
        f2bf2(v0[e], h_, l_);
        hh[e] = (short)h_;
        ll[e] = (short)l_;
      }
#pragma unroll
      for (int e = 0; e < 4; ++e) {
        unsigned short h_, l_;
        f2bf2(v1[e], h_, l_);
        hh[4 + e] = (short)h_;
        ll[4 + e] = (short)l_;
      }
      Ah[g][kc] = hh;
      Al[g][kc] = ll;
    }
  }
  const f32x4 bhhN = *(const f32x4*)(bhh + 128 + j0);

  int ml = len;
#pragma unroll
  for (int m = 1; m < 16; m <<= 1) ml = max(ml, __shfl_xor(ml, m, 64));
  const int ml8 = (ml + 7) & ~7;

  const int kcW = w >> 1;
  const int koffW = (w & 1) * 16 + lg * 4;
  {
    uint2 z2;
    z2.x = 0u; z2.y = 0u;
    *(uint2*)&hbuf[0][0][kcW][b16][koffW] = z2;
    *(uint2*)&hbuf[0][1][kcW][b16][koffW] = z2;
  }
  f32x4 h = {0.f, 0.f, 0.f, 0.f};
  asm volatile("s_waitcnt lgkmcnt(0)" ::: "memory");
  __builtin_amdgcn_s_barrier();
  __builtin_amdgcn_sched_barrier(0);

  // per-lane walking pointers, clamped at the last valid row
  const int p0 = dir ? (len - 1) : 0;
  const float* gp = gx + (size_t)(start + p0) * 384 + dirbase + j0;
  float* hp = hs + (size_t)(start + p0) * 128 + dir * 64 + j0;
  const ptrdiff_t gstep = dir ? -384 : 384;
  const ptrdiff_t hstep = dir ? -128 : 128;

  // fill 8-deep pipeline (steps 0..7, clamped)
  f32x4 Gr[8], Gz[8], Gn[8];
#pragma unroll
  for (int i = 0; i < 8; ++i) {
    Gr[i] = *(const f32x4*)gp;
    Gz[i] = *(const f32x4*)(gp + 64);
    Gn[i] = *(const f32x4*)(gp + 128);
    if (i + 1 < len) gp += gstep;
  }

#define SCAN_STEP(K)                                                           \
  {                                                                            \
    const int s = t + (K);                                                     \
    short8 bhf0 = *(const short8*)&hbuf[(K) & 1][0][0][b16][lg * 8];           \
    short8 bhf1 = *(const short8*)&hbuf[(K) & 1][0][1][b16][lg * 8];           \
    short8 blf0 = *(const short8*)&hbuf[(K) & 1][1][0][b16][lg * 8];           \
    short8 blf1 = *(const short8*)&hbuf[(K) & 1][1][1][b16][lg * 8];           \
    f32x4 ara = Gr[K], aza = Gz[K], ana = bhhN;                                \
    f32x4 zz = {0.f, 0.f, 0.f, 0.f};                                           \
    f32x4 arb = zz, azb = zz, anb = zz;                                        \
    ara = mfma16(Ah[0][0], bhf0, ara);                                         \
    aza = mfma16(Ah[1][0], bhf0, aza);                                         \
    ana = mfma16(Ah[2][0], bhf0, ana);                                         \
    arb = mfma16(Ah[0][1], bhf1, arb);                                         \
    azb = mfma16(Ah[1][1], bhf1, azb);                                         \
    anb = mfma16(Ah[2][1], bhf1, anb);                                         \
    ara = mfma16(Ah[0][0], blf0, ara);                                         \
    aza = mfma16(Ah[1][0], blf0, aza);                                         \
    ana = mfma16(Ah[2][0], blf0, ana);                                         \
    arb = mfma16(Ah[0][1], blf1, arb);                                         \
    azb = mfma16(Ah[1][1], blf1, azb);                                         \
    anb = mfma16(Ah[2][1], blf1, anb);                                         \
    ara = mfma16(Al[0][0], bhf0, ara);                                         \
    aza = mfma16(Al[1][0], bhf0, aza);                                         \
    ana = mfma16(Al[2][0], bhf0, ana);                                         \
    arb = mfma16(Al[0][1], bhf1, arb);                                         \
    azb = mfma16(Al[1][1], bhf1, azb);                                         \
    anb = mfma16(Al[2][1], bhf1, anb);                                         \
    f32x4 gn = Gn[K];                                                          \
    /* re-issue this slot's loads for step s+8 (clamped) */                    \
    Gr[K] = *(const f32x4*)gp;                                                 \
    Gz[K] = *(const f32x4*)(gp + 64);                                          \
    Gn[K] = *(const f32x4*)(gp + 128);                                         \
    if (s + 9 < len) gp += gstep;                                              \
    f32x4 ar = ara + arb, az = aza + azb, an = ana + anb;                      \
    f32x4 hn;                                                                  \
    _Pragma("unroll") for (int q = 0; q < 4; ++q) {                            \
      float r = sigm(ar[q]);                                                   \
      float z = sigm(az[q]);                                                   \
      float n = tanhft(gn[q] + r * an[q]);                                     \
      hn[q] = z * (h[q] - n) + n;                                              \
    }                                                                          \
    const bool valid = (s < len);                                              \
    _Pragma("unroll") for (int q = 0; q < 4; ++q) h[q] = valid ? hn[q] : h[q]; \
    *(f32x4*)hp = h; /* frozen-h makes the padded-step store idempotent */     \
    if (s + 1 < len) hp += hstep;                                              \
    /* exact hi/lo split via truncation: lo = h - trunc16(h), |err|~2^-17 */   \
    unsigned int b0 = __float_as_uint(h[0]);                                   \
    unsigned int b1 = __float_as_uint(h[1]);                                   \
    unsigned int b2 = __float_as_uint(h[2]);                                   \
    unsigned int b3 = __float_as_uint(h[3]);                                   \
    uint2 whi;                                                                 \
    whi.x = (b0 >> 16) | (b1 & 0xFFFF0000u);                                   \
    whi.y = (b2 >> 16) | (b3 & 0xFFFF0000u);                                   \
    float l0 = h[0] - __uint_as_float(b0 & 0xFFFF0000u);                       \
    float l1 = h[1] - __uint_as_float(b1 & 0xFFFF0000u);                       \
    float l2 = h[2] - __uint_as_float(b2 & 0xFFFF0000u);                       \
    float l3 = h[3] - __uint_as_float(b3 & 0xFFFF0000u);                       \
    uint2 wlo;                                                                 \
    wlo.x = (__float_as_uint(l0) >> 16) | (__float_as_uint(l1) & 0xFFFF0000u); \
    wlo.y = (__float_as_uint(l2) >> 16) | (__float_as_uint(l3) & 0xFFFF0000u); \
    *(uint2*)&hbuf[((K) + 1) & 1][0][kcW][b16][koffW] = whi;                   \
    *(uint2*)&hbuf[((K) + 1) & 1][1][kcW][b16][koffW] = wlo;                   \
    asm volatile("s_waitcnt lgkmcnt(0)" ::: "memory");                         \
    __builtin_amdgcn_s_barrier();                                              \
    __builtin_amdgcn_sched_barrier(0);                                         \
  }

#pragma unroll 1
  for (int t = 0; t < ml8; t += 8) {
    SCAN_STEP(0)
    SCAN_STEP(1)
    SCAN_STEP(2)
    SCAN_STEP(3)
    SCAN_STEP(4)
    SCAN_STEP(5)
    SCAN_STEP(6)
    SCAN_STEP(7)
  }
#undef SCAN_STEP
}

// --------------------------------------------------------------- K4: MLP GEMM
__global__ __launch_bounds__(256) void k_gemm_mlp(
    const float* __restrict__ hs, const unsigned short* __restrict__ Bhi,
    const unsigned short* __restrict__ Blo, const float* __restrict__ bm,
    const float* __restrict__ ctx, float* __restrict__ mlp,
    float* __restrict__ scores, int total) {
  __shared__ unsigned short Ahi[64][136];
  __shared__ unsigned short Alo[64][136];
  const int tid = threadIdx.x;
  const int base = blockIdx.x * 64;
  {
    int row = tid & 63, cc = tid >> 6;
    int grow = base + row;
    if (grow >= total) grow = total - 1;
    const float* src = hs + (size_t)grow * 128 + cc * 32;
#pragma unroll
    for (int u = 0; u < 8; ++u) {
      f32x4 v = *(const f32x4*)(src + u * 4);
#pragma unroll
      for (int e = 0; e < 4; ++e) {
        unsigned short h_, l_;
        f2bf2(v[e], h_, l_);
        Ahi[row][cc * 32 + u * 4 + e] = h_;
        Alo[row][cc * 32 + u * 4 + e] = l_;
      }
    }
  }
  __syncthreads();
  const int w = tid >> 6, l = tid & 63;
  const int lr = l & 15, lg = l >> 4;
  short8 afh[4], afl[4];
#pragma unroll
  for (int kc = 0; kc < 4; ++kc) {
    afh[kc] = *(const short8*)&Ahi[w * 16 + lr][kc * 32 + lg * 8];
    afl[kc] = *(const short8*)&Alo[w * 16 + lr][kc * 32 + lg * 8];
  }
  float sc0 = 0.f, sc1 = 0.f, sc2 = 0.f, sc3 = 0.f;
#pragma unroll 1
  for (int nt = 0; nt < 8; ++nt) {
    const int ncol = nt * 16 + lr;
    const float bias = bm[ncol];
    const float cv = ctx[ncol];
    f32x4 acc = {bias, bias, bias, bias};
#pragma unroll
    for (int kc = 0; kc < 4; ++kc) {
      short8 bh = *(const short8*)(Bhi + (size_t)ncol * 128 + kc * 32 + lg * 8);
      short8 bl = *(const short8*)(Blo + (size_t)ncol * 128 + kc * 32 + lg * 8);
      acc = mfma16(afh[kc], bh, acc);
      acc = mfma16(afl[kc], bh, acc);
      acc = mfma16(afh[kc], bl, acc);
    }
    const int r0 = base + w * 16 + lg * 4;
    float tv0 = tanhft(acc[0]);
    float tv1 = tanhft(acc[1]);
    float tv2 = tanhft(acc[2]);
    float tv3 = tanhft(acc[3]);
    if (r0 + 0 < total) mlp[(size_t)(r0 + 0) * 128 + ncol] = tv0;
    if (r0 + 1 < total) mlp[(size_t)(r0 + 1) * 128 + ncol] = tv1;
    if (r0 + 2 < total) mlp[(size_t)(r0 + 2) * 128 + ncol] = tv2;
    if (r0 + 3 < total) mlp[(size_t)(r0 + 3) * 128 + ncol] = tv3;
    sc0 += tv0 * cv;
    sc1 += tv1 * cv;
    sc2 += tv2 * cv;
    sc3 += tv3 * cv;
  }
#pragma unroll
  for (int m = 1; m < 16; m <<= 1) {
    sc0 += __shfl_xor(sc0, m, 64);
    sc1 += __shfl_xor(sc1, m, 64);
    sc2 += __shfl_xor(sc2, m, 64);
    sc3 += __shfl_xor(sc3, m, 64);
  }
  if (lr == 0) {
    const int r0 = base + w * 16 + lg * 4;
    if (r0 + 0 < total) scores[r0 + 0] = sc0;
    if (r0 + 1 < total) scores[r0 + 1] = sc1;
    if (r0 + 2 < total) scores[r0 + 2] = sc2;
    if (r0 + 3 < total) scores[r0 + 3] = sc3;
  }
}

// ------------------------------------------------------------------- K5: pool
__global__ __launch_bounds__(512) void k_pool(
    const float* __restrict__ scores, const float* __restrict__ mlp,
    const int* __restrict__ off, const int* __restrict__ seqlens,
    float* __restrict__ out) {
  const int s = blockIdx.x;
  const int tid = threadIdx.x;
  const int len = seqlens[s];
  const int st = off[s];
  const int col = tid & 127, slice = tid >> 7;
  float m = (tid < len) ? scores[st + tid] : -1e30f;
#pragma unroll
  for (int d = 1; d < 64; d <<= 1) m = fmaxf(m, __shfl_xor(m, d, 64));
  __shared__ float wmx[8];
  if ((tid & 63) == 0) wmx[tid >> 6] = m;
  __syncthreads();
  m = wmx[0];
#pragma unroll
  for (int i = 1; i < 8; ++i) m = fmaxf(m, wmx[i]);
  float acc = 0.f, ws = 0.f;
  for (int t = slice; t < len; t += 4) {
    float wv = __expf(scores[st + t] - m);
    ws += wv;
    acc += wv * mlp[(size_t)(st + t) * 128 + col];
  }
  __shared__ float accs[4][128];
  __shared__ float wss[4];
  accs[slice][col] = acc;
  if (col == 0) wss[slice] = ws;
  __syncthreads();
  if (tid < 128) {
    float a = accs[0][tid] + accs[1][tid] + accs[2][tid] + accs[3][tid];
    float wsum = wss[0] + wss[1] + wss[2] + wss[3];
    out[(size_t)s * 128 + tid] = a * rcpf(wsum);
  }
}

// ---------------------------------------------------------------------- launch
extern "C" void kernel_launch(void* const* d_in, const int* in_sizes, int n_in,
                              void* d_out, int out_size, void* d_ws, size_t ws_size,
                              hipStream_t stream) {
  const float* seqs = (const float*)d_in[0];
  const int* seqlens = (const int*)d_in[1];
  const float* Wih_f = (const float*)d_in[2];
  const float* Whh_f = (const float*)d_in[3];
  const float* bih_f = (const float*)d_in[4];
  const float* bhh_f = (const float*)d_in[5];
  const float* Wih_b = (const float*)d_in[6];
  const float* Whh_b = (const float*)d_in[7];
  const float* bih_b = (const float*)d_in[8];
  const float* bhh_b = (const float*)d_in[9];
  const float* Wm = (const float*)d_in[10];
  const float* bm = (const float*)d_in[11];
  const float* ctx = (const float*)d_in[12];

  const int total = in_sizes[0] / 128;

  char* ws = (char*)d_ws;
  size_t o = 0;
  auto alloc = [&](size_t bytes) {
    size_t r = o;
    o = (o + bytes + 255) & ~(size_t)255;
    return r;
  };
  int* off = (int*)(ws + alloc(513 * 4));
  unsigned short* Wcat_hi = (unsigned short*)(ws + alloc(384 * 128 * 2));
  unsigned short* Wcat_lo = (unsigned short*)(ws + alloc(384 * 128 * 2));
  float* biasA = (float*)(ws + alloc(384 * 4));
  unsigned short* Wm_hi = (unsigned short*)(ws + alloc(128 * 128 * 2));
  unsigned short* Wm_lo = (unsigned short*)(ws + alloc(128 * 128 * 2));
  float* scores = (float*)(ws + alloc((size_t)total * 4));
  float* gxbuf = (float*)(ws + alloc((size_t)total * 384 * 4));
  float* hsbuf = (float*)(ws + alloc((size_t)total * 128 * 4));
  float* mlp = gxbuf;  // reuse gx region after the scan

  k_offsets<<<1, 512, 0, stream>>>(seqlens, off);
  k_prep<<<64, 256, 0, stream>>>(Wih_f, Wih_b, bih_f, bhh_f, bih_b, bhh_b, Wm,
                                 Wcat_hi, Wcat_lo, biasA, Wm_hi, Wm_lo);
  const int mt = (total + 63) / 64;
  k_gemm_gx<<<mt, 256, 0, stream>>>(seqs, Wcat_hi, Wcat_lo, biasA, gxbuf, total);
  k_scan<<<64, 256, 0, stream>>>(gxbuf, off, seqlens, Whh_f, Whh_b, bhh_f, bhh_b, hsbuf);
  k_gemm_mlp<<<mt, 256, 0, stream>>>(hsbuf, Wm_hi, Wm_lo, bm, ctx, mlp, scores, total);
  k_pool<<<512, 512, 0, stream>>>(scores, mlp, off, seqlens, (float*)d_out);
}